// Round 4
// baseline (160.960 us; speedup 1.0000x reference)
//
#include <hip/hip_runtime.h>
#include <hip/hip_bf16.h>

typedef __bf16 bf16;
typedef __attribute__((ext_vector_type(8))) __bf16 bf16x8;
typedef __attribute__((ext_vector_type(4))) __bf16 bf16x4;
typedef __attribute__((ext_vector_type(4))) float f32x4;

#define BAR() __builtin_amdgcn_s_barrier()

__device__ __forceinline__ void async_load16(const void* g, void* l) {
    __builtin_amdgcn_global_load_lds(
        (const __attribute__((address_space(1))) void*)g,
        (__attribute__((address_space(3))) void*)l, 16, 0, 0);
}

// ---------- kernel 1: per-block partial sum of |w| (deterministic tree) ----------
__global__ __launch_bounds__(256) void k_abs_part(const float* __restrict__ w, int n,
                                                  double* __restrict__ part) {
    __shared__ double sd[256];
    const int per_block = n / gridDim.x;
    const int base = blockIdx.x * per_block;
    double s = 0.0;
    for (int i = threadIdx.x; i < per_block; i += 256)
        s += (double)fabsf(w[base + i]);
    sd[threadIdx.x] = s;
    __syncthreads();
    for (int off = 128; off > 0; off >>= 1) {
        if (threadIdx.x < off) sd[threadIdx.x] += sd[threadIdx.x + off];
        __syncthreads();
    }
    if (threadIdx.x == 0) part[blockIdx.x] = sd[0];
}

// ---------- kernel 2: finalize delta = 0.7 * mean(|w|) ----------
__global__ __launch_bounds__(256) void k_delta(const double* __restrict__ part, int npart,
                                               int n, float* __restrict__ delta) {
    __shared__ double sd[256];
    double s = 0.0;
    for (int i = threadIdx.x; i < npart; i += 256) s += part[i];
    sd[threadIdx.x] = s;
    __syncthreads();
    for (int off = 128; off > 0; off >>= 1) {
        if (threadIdx.x < off) sd[threadIdx.x] += sd[threadIdx.x + off];
        __syncthreads();
    }
    if (threadIdx.x == 0) *delta = (float)(0.7 * sd[0] / (double)n);
}

// ---------- kernel 3: ternary-quantize weight to bf16 {-1,0,1} ----------
__global__ __launch_bounds__(256) void k_quant(const float* __restrict__ w,
                                               const float* __restrict__ dp,
                                               bf16* __restrict__ wt, int n4) {
    const float d = *dp;
    const int i = blockIdx.x * 256 + threadIdx.x;
    if (i >= n4) return;
    const float4 v = ((const float4*)w)[i];
    bf16x4 o;
    o[0] = (bf16)((v.x > d) ? 1.0f : (v.x < -d) ? -1.0f : 0.0f);
    o[1] = (bf16)((v.y > d) ? 1.0f : (v.y < -d) ? -1.0f : 0.0f);
    o[2] = (bf16)((v.z > d) ? 1.0f : (v.z < -d) ? -1.0f : 0.0f);
    o[3] = (bf16)((v.w > d) ? 1.0f : (v.w < -d) ? -1.0f : 0.0f);
    *(bf16x4*)(wt + (size_t)i * 4) = o;
}

// ---------- helper: stage one 128x64 bf16 half-tile via global_load_lds ----------
__device__ __forceinline__ void stage_half(const bf16* __restrict__ srch, int K, int kt,
                                           char* dst, int t) {
    #pragma unroll
    for (int r = 0; r < 2; ++r) {
        const int c  = (r << 9) + t;
        const int rp = c >> 3;
        const int s  = (c & 7) ^ ((t >> 3) & 7);
        async_load16(srch + (size_t)rp * K + (kt << 6) + (s << 3), dst + (c << 4));
    }
}

// ---------- kernel 4: 256x256 8-phase GEMM, fused fp32->bf16 A staging ----------
// C[m][n] = alpha * sum_k A[m][k]*Wt[n][k] + bias[n].  512 thr = 8 waves (2M x 4N),
// BK=64, LDS 128KB.  A: fp32 global -> regs (1-2 phase lookahead) -> cvt -> swizzled
// ds_write.  B: bf16 wt via global_load_lds (linear dest + pre-swizzled global src).
// Per-iter stage plan: P0 LAa(h0,ktB) | P2 WAa->par1, SBx2(kA2,par0), LAb(h1,ktB) |
// P3 vmcnt0, WAb->par1 | P4 LAa(h0,kA2) | P6 WAa->par0, SBx2(kB2,par1), LAb(h1,kA2) |
// P7 vmcnt0, WAb->par0.  lgkmcnt(0) before P3/P7 end-barriers covers ds_writes.
__global__ __launch_bounds__(512, 2) void k_gemm8(const float* __restrict__ Afp,
                                                  const bf16* __restrict__ Bw,
                                                  const float* __restrict__ alphap,
                                                  const float* __restrict__ bias,
                                                  float* __restrict__ C,
                                                  int M, int N, int K) {
    __shared__ __align__(16) char lds[2][2][2][16384];  // [parity][A=0/B=1][half][16KB]

    const int t    = threadIdx.x;
    const int lane = t & 63;
    const int w    = t >> 6;
    const int wm   = w >> 2;
    const int wn   = w & 3;
    const int lr   = lane & 15;
    const int hi   = lane >> 4;

    const int nbn = N >> 8;
    const int cpx = gridDim.x >> 3;
    const int lid = (blockIdx.x & 7) * cpx + (blockIdx.x >> 3);
    const int bn0 = (lid % nbn) << 8;
    const int bm0 = (lid / nbn) << 8;

    const bf16* Bsrc[2] = { Bw + (size_t)bn0 * K, Bw + (size_t)(bn0 + 128) * K };

    f32x4 acc[8][4] = {};
    bf16x8 afq[4][2], bfA[2][2], bfB[2][2];
    float4 a0, a1, a2, a3;   // av_a: half0 staging regs
    float4 b0, b1, b2, b3;   // av_b: half1 staging regs

    const int x0 = ((hi ^ (lr & 7)) << 4);
    const int x1 = (((4 + hi) ^ (lr & 7)) << 4);

    // A staging geometry: thread owns rows (t>>3) and 64+(t>>3), slot t&7
    const int a_r0 = t >> 3;
    const int a_sl = t & 7;
    const int a_sw = ((a_sl ^ (a_r0 & 7)) << 4);   // same for row and row+64

#define LA(H, KT, V0, V1, V2, V3) do { \
    const float* _p = Afp + (size_t)(bm0 + ((H) << 7) + a_r0) * K + ((KT) << 6) + (a_sl << 3); \
    V0 = *(const float4*)_p;                    V1 = *(const float4*)(_p + 4); \
    V2 = *(const float4*)(_p + (size_t)64 * K); V3 = *(const float4*)(_p + (size_t)64 * K + 4); \
} while (0)

#define WA(PAR, H, V0, V1, V2, V3) do { \
    char* _d = &lds[PAR][0][H][0]; \
    bf16x8 _h0, _h1; \
    _h0[0]=(bf16)V0.x; _h0[1]=(bf16)V0.y; _h0[2]=(bf16)V0.z; _h0[3]=(bf16)V0.w; \
    _h0[4]=(bf16)V1.x; _h0[5]=(bf16)V1.y; _h0[6]=(bf16)V1.z; _h0[7]=(bf16)V1.w; \
    _h1[0]=(bf16)V2.x; _h1[1]=(bf16)V2.y; _h1[2]=(bf16)V2.z; _h1[3]=(bf16)V2.w; \
    _h1[4]=(bf16)V3.x; _h1[5]=(bf16)V3.y; _h1[6]=(bf16)V3.z; _h1[7]=(bf16)V3.w; \
    *(bf16x8*)(_d + a_r0 * 128 + a_sw) = _h0; \
    *(bf16x8*)(_d + (64 + a_r0) * 128 + a_sw) = _h1; \
} while (0)

#define LDA_Q(MQ, PAR) do { \
    const char* _b = &lds[PAR][0][wm][0]; \
    _Pragma("unroll") \
    for (int m = 0; m < 4; ++m) { \
        const int _r = ((MQ) << 6) + (m << 4) + lr; \
        afq[m][0] = *(const bf16x8*)(_b + _r * 128 + x0); \
        afq[m][1] = *(const bf16x8*)(_b + _r * 128 + x1); \
    } \
} while (0)

#define LDB_Q(DST, NQ, PAR) do { \
    const char* _b = &lds[PAR][1][wn >> 1][0]; \
    _Pragma("unroll") \
    for (int n = 0; n < 2; ++n) { \
        const int _r = ((wn & 1) << 6) + ((((NQ) << 1) + n) << 4) + lr; \
        DST[n][0] = *(const bf16x8*)(_b + _r * 128 + x0); \
        DST[n][1] = *(const bf16x8*)(_b + _r * 128 + x1); \
    } \
} while (0)

#define MF_Q(MQ, NQ, BF) do { \
    __builtin_amdgcn_s_setprio(1); \
    _Pragma("unroll") \
    for (int ks = 0; ks < 2; ++ks) \
        _Pragma("unroll") \
        for (int m = 0; m < 4; ++m) { \
            acc[((MQ)<<2)+m][((NQ)<<1)+0] = __builtin_amdgcn_mfma_f32_16x16x32_bf16(afq[m][ks], BF[0][ks], acc[((MQ)<<2)+m][((NQ)<<1)+0], 0, 0, 0); \
            acc[((MQ)<<2)+m][((NQ)<<1)+1] = __builtin_amdgcn_mfma_f32_16x16x32_bf16(afq[m][ks], BF[1][ks], acc[((MQ)<<2)+m][((NQ)<<1)+1], 0, 0, 0); \
        } \
    __builtin_amdgcn_s_setprio(0); \
} while (0)

#define VMCNT0() asm volatile("s_waitcnt vmcnt(0)" ::: "memory")
#define LGKM0()  asm volatile("s_waitcnt lgkmcnt(0)" ::: "memory")

    // ---------------- prologue: kt0 (par0) A+B, kt1 (par1) B ----------------
    LA(0, 0, a0, a1, a2, a3);
    LA(1, 0, b0, b1, b2, b3);
    stage_half(Bsrc[0], K, 0, &lds[0][1][0][0], t);
    stage_half(Bsrc[1], K, 0, &lds[0][1][1][0], t);
    stage_half(Bsrc[0], K, 1, &lds[1][1][0][0], t);
    stage_half(Bsrc[1], K, 1, &lds[1][1][1][0], t);
    VMCNT0();
    WA(0, 0, a0, a1, a2, a3);
    WA(0, 1, b0, b1, b2, b3);
    LGKM0();
    BAR();

    const int NI = K >> 7;   // 8 iterations, 2 K-tiles each
    for (int i = 0; i < NI; ++i) {
        const int  ktB  = 2 * i + 1;
        const bool last = (i == NI - 1);
        const int  kA2  = last ? 0 : 2 * i + 2;   // wrap: valid addr, dead data
        const int  kB2  = last ? 1 : 2 * i + 3;

        // P0
        LDA_Q(0, 0); LDB_Q(bfA, 0, 0);
        LA(0, ktB, a0, a1, a2, a3);
        BAR(); MF_Q(0, 0, bfA); BAR();
        // P1
        LDB_Q(bfB, 1, 0);
        BAR(); MF_Q(0, 1, bfB); BAR();
        // P2
        LDA_Q(1, 0);
        WA(1, 0, a0, a1, a2, a3);                 // par1 A half0 (compiler waits LAa)
        stage_half(Bsrc[0], K, kA2, &lds[0][1][0][0], t);
        stage_half(Bsrc[1], K, kA2, &lds[0][1][1][0], t);
        LA(1, ktB, b0, b1, b2, b3);
        BAR(); MF_Q(1, 1, bfB); BAR();
        // P3
        VMCNT0();                                 // drains SB(par0) + LAb
        WA(1, 1, b0, b1, b2, b3);
        LGKM0();
        BAR(); MF_Q(1, 0, bfA); BAR();
        // P4
        LDA_Q(0, 1); LDB_Q(bfA, 0, 1);
        LA(0, kA2, a0, a1, a2, a3);
        BAR(); MF_Q(0, 0, bfA); BAR();
        // P5
        LDB_Q(bfB, 1, 1);
        BAR(); MF_Q(0, 1, bfB); BAR();
        // P6
        LDA_Q(1, 1);
        WA(0, 0, a0, a1, a2, a3);                 // par0 A half0 for next iter
        stage_half(Bsrc[0], K, kB2, &lds[1][1][0][0], t);
        stage_half(Bsrc[1], K, kB2, &lds[1][1][1][0], t);
        LA(1, kA2, b0, b1, b2, b3);
        BAR(); MF_Q(1, 1, bfB); BAR();
        // P7
        VMCNT0();                                 // drains SB(par1) + LAb
        WA(0, 1, b0, b1, b2, b3);
        LGKM0();
        BAR(); MF_Q(1, 0, bfA); BAR();
    }

    // ---------------- epilogue ----------------
    const float alpha = *alphap;
    float bv[4];
    #pragma unroll
    for (int nf = 0; nf < 4; ++nf) bv[nf] = bias[bn0 + (wn << 6) + (nf << 4) + lr];

    #pragma unroll
    for (int mf = 0; mf < 8; ++mf) {
        const int grow = bm0 + (wm << 7) + (mf << 4) + (hi << 2);
        #pragma unroll
        for (int nf = 0; nf < 4; ++nf) {
            const int gcol = bn0 + (wn << 6) + (nf << 4) + lr;
            #pragma unroll
            for (int r = 0; r < 4; ++r)
                C[(size_t)(grow + r) * N + gcol] = alpha * acc[mf][nf][r] + bv[nf];
        }
    }
#undef LA
#undef WA
#undef LDA_Q
#undef LDB_Q
#undef MF_Q
#undef VMCNT0
#undef LGKM0
}

// ---------- fallback GEMM (round-1 proven): fp32 A staged in-kernel ----------
__global__ __launch_bounds__(256) void k_gemm_fb(const float* __restrict__ A,
                                                 const bf16* __restrict__ Bw,
                                                 const float* __restrict__ alphap,
                                                 const float* __restrict__ bias,
                                                 float* __restrict__ C,
                                                 int M, int N, int K) {
    __shared__ bf16 As[128 * 32];
    __shared__ bf16 Bs[128 * 32];
    const int t = threadIdx.x, lane = t & 63, wave = t >> 6;
    const int nbm = M >> 7;
    const int bm0 = (blockIdx.x % nbm) << 7;
    const int bn0 = (blockIdx.x / nbm) << 7;
    const int wr = (wave >> 1) << 6, wc = (wave & 1) << 6;
    f32x4 acc[4][4] = {};
    const int lr = lane & 15, lk = (lane >> 4) << 3;
    for (int k0 = 0; k0 < K; k0 += 32) {
        #pragma unroll
        for (int j = 0; j < 2; ++j) {
            const int c = t + j * 256;
            async_load16(Bw + (size_t)(bn0 + (c >> 2)) * K + k0 + ((c & 3) << 3),
                         (char*)Bs + j * 4096 + wave * 1024);
        }
        #pragma unroll
        for (int i = 0; i < 4; ++i) {
            const int idx = t + i * 256;
            const int row = idx >> 3, c4 = (idx & 7) << 2;
            const float4 v = *(const float4*)(A + (size_t)(bm0 + row) * K + k0 + c4);
            bf16x4 h;
            h[0] = (bf16)v.x; h[1] = (bf16)v.y; h[2] = (bf16)v.z; h[3] = (bf16)v.w;
            *(bf16x4*)(As + row * 32 + c4) = h;
        }
        __syncthreads();
        bf16x8 af[4], bfr[4];
        #pragma unroll
        for (int m = 0; m < 4; ++m) af[m] = *(const bf16x8*)(As + (wr + m * 16 + lr) * 32 + lk);
        #pragma unroll
        for (int n = 0; n < 4; ++n) bfr[n] = *(const bf16x8*)(Bs + (wc + n * 16 + lr) * 32 + lk);
        #pragma unroll
        for (int m = 0; m < 4; ++m)
            #pragma unroll
            for (int n = 0; n < 4; ++n)
                acc[m][n] = __builtin_amdgcn_mfma_f32_16x16x32_bf16(af[m], bfr[n], acc[m][n], 0, 0, 0);
        __syncthreads();
    }
    const float alpha = *alphap;
    #pragma unroll
    for (int m = 0; m < 4; ++m)
        #pragma unroll
        for (int n = 0; n < 4; ++n) {
            const int gcol = bn0 + wc + n * 16 + lr;
            const float bv = bias[gcol];
            #pragma unroll
            for (int r = 0; r < 4; ++r) {
                const int grow = bm0 + wr + m * 16 + ((lane >> 4) << 2) + r;
                C[(size_t)grow * N + gcol] = alpha * acc[m][n][r] + bv;
            }
        }
}

extern "C" void kernel_launch(void* const* d_in, const int* in_sizes, int n_in,
                              void* d_out, int out_size, void* d_ws, size_t ws_size,
                              hipStream_t stream) {
    const float* x     = (const float*)d_in[0];
    const float* wgt   = (const float*)d_in[1];
    const float* alpha = (const float*)d_in[2];
    const float* bias  = (const float*)d_in[3];
    float* out = (float*)d_out;

    const int wn   = in_sizes[1];        // 1048576
    const int dout = in_sizes[3];        // 1024
    const int din  = wn / dout;          // 1024
    const int m    = in_sizes[0] / din;  // 32768

    char* ws = (char*)d_ws;
    float*  delta = (float*)ws;                  // [0,4)
    double* part  = (double*)(ws + 64);          // 256 doubles
    bf16*   wt    = (bf16*)(ws + 8192);          // 2 MiB ternary weights

    k_abs_part<<<256, 256, 0, stream>>>(wgt, wn, part);
    k_delta<<<1, 256, 0, stream>>>(part, 256, wn, delta);
    k_quant<<<(wn / 4 + 255) / 256, 256, 0, stream>>>(wgt, delta, wt, wn / 4);

    if ((m % 256) == 0 && (dout % 256) == 0 && (din % 128) == 0) {
        dim3 grid((m / 256) * (dout / 256));
        k_gemm8<<<grid, 512, 0, stream>>>(x, wt, alpha, bias, out, m, dout, din);
    } else {
        dim3 grid((m / 128) * (dout / 128));
        k_gemm_fb<<<grid, 256, 0, stream>>>(x, wt, alpha, bias, out, m, dout, din);
    }
}

// Round 5
// 145.223 us; speedup vs baseline: 1.1084x; 1.1084x over previous
//
#include <hip/hip_runtime.h>
#include <hip/hip_bf16.h>

typedef __bf16 bf16;
typedef __attribute__((ext_vector_type(8))) __bf16 bf16x8;
typedef __attribute__((ext_vector_type(4))) __bf16 bf16x4;
typedef __attribute__((ext_vector_type(4))) float f32x4;

#define BAR() __builtin_amdgcn_s_barrier()

__device__ __forceinline__ void async_load16(const void* g, void* l) {
    __builtin_amdgcn_global_load_lds(
        (const __attribute__((address_space(1))) void*)g,
        (__attribute__((address_space(3))) void*)l, 16, 0, 0);
}

// ---------- kernel 1: per-block partial sum of |w| (deterministic tree) ----------
__global__ __launch_bounds__(256) void k_abs_part(const float* __restrict__ w, int n,
                                                  double* __restrict__ part) {
    __shared__ double sd[256];
    const int per_block = n / gridDim.x;
    const int base = blockIdx.x * per_block;
    double s = 0.0;
    for (int i = threadIdx.x; i < per_block; i += 256)
        s += (double)fabsf(w[base + i]);
    sd[threadIdx.x] = s;
    __syncthreads();
    for (int off = 128; off > 0; off >>= 1) {
        if (threadIdx.x < off) sd[threadIdx.x] += sd[threadIdx.x + off];
        __syncthreads();
    }
    if (threadIdx.x == 0) part[blockIdx.x] = sd[0];
}

// ---------- kernel 2: finalize delta = 0.7 * mean(|w|) ----------
__global__ __launch_bounds__(256) void k_delta(const double* __restrict__ part, int npart,
                                               int n, float* __restrict__ delta) {
    __shared__ double sd[256];
    double s = 0.0;
    for (int i = threadIdx.x; i < npart; i += 256) s += part[i];
    sd[threadIdx.x] = s;
    __syncthreads();
    for (int off = 128; off > 0; off >>= 1) {
        if (threadIdx.x < off) sd[threadIdx.x] += sd[threadIdx.x + off];
        __syncthreads();
    }
    if (threadIdx.x == 0) *delta = (float)(0.7 * sd[0] / (double)n);
}

// ---------- kernel 3: ternary-quantize weight to bf16 {-1,0,1} ----------
__global__ __launch_bounds__(256) void k_quant(const float* __restrict__ w,
                                               const float* __restrict__ dp,
                                               bf16* __restrict__ wt, int n4) {
    const float d = *dp;
    const int i = blockIdx.x * 256 + threadIdx.x;
    if (i >= n4) return;
    const float4 v = ((const float4*)w)[i];
    bf16x4 o;
    o[0] = (bf16)((v.x > d) ? 1.0f : (v.x < -d) ? -1.0f : 0.0f);
    o[1] = (bf16)((v.y > d) ? 1.0f : (v.y < -d) ? -1.0f : 0.0f);
    o[2] = (bf16)((v.z > d) ? 1.0f : (v.z < -d) ? -1.0f : 0.0f);
    o[3] = (bf16)((v.w > d) ? 1.0f : (v.w < -d) ? -1.0f : 0.0f);
    *(bf16x4*)(wt + (size_t)i * 4) = o;
}

// ---------- helper: stage one 128x64 bf16 half-tile via global_load_lds ----------
__device__ __forceinline__ void stage_half(const bf16* __restrict__ srch, int K, int kt,
                                           char* dst, int t) {
    #pragma unroll
    for (int r = 0; r < 2; ++r) {
        const int c  = (r << 9) + t;
        const int rp = c >> 3;
        const int s  = (c & 7) ^ ((t >> 3) & 7);
        async_load16(srch + (size_t)rp * K + (kt << 6) + (s << 3), dst + (c << 4));
    }
}

// ---------- kernel 4: 256x256 8-phase GEMM, fused fp32->bf16 A staging ----------
// T4-correct version: NO manual vmcnt in the main loop.  All waits are the
// compiler's counted auto-waits on the A register loads; since vmcnt is one
// FIFO, those waits drain the older interleaved B global_load_lds exactly when
// their consumers need them, while the freshest B-stage always stays in flight
// (issued P2 -> drained by P6's auto-wait -> read next-iter P0: 4-6 phases).
// A loads have 2-phase issue->consume gaps (P0->P2, P1->P3, P4->P6, P5->P7).
__global__ __launch_bounds__(512, 2) void k_gemm8(const float* __restrict__ Afp,
                                                  const bf16* __restrict__ Bw,
                                                  const float* __restrict__ alphap,
                                                  const float* __restrict__ bias,
                                                  float* __restrict__ C,
                                                  int M, int N, int K) {
    __shared__ __align__(16) char lds[2][2][2][16384];  // [parity][A=0/B=1][half][16KB]

    const int t    = threadIdx.x;
    const int lane = t & 63;
    const int w    = t >> 6;
    const int wm   = w >> 2;
    const int wn   = w & 3;
    const int lr   = lane & 15;
    const int hi   = lane >> 4;

    const int nbn = N >> 8;
    const int cpx = gridDim.x >> 3;
    const int lid = (blockIdx.x & 7) * cpx + (blockIdx.x >> 3);
    const int bn0 = (lid % nbn) << 8;
    const int bm0 = (lid / nbn) << 8;

    const bf16* Bsrc[2] = { Bw + (size_t)bn0 * K, Bw + (size_t)(bn0 + 128) * K };

    f32x4 acc[8][4] = {};
    bf16x8 afq[4][2], bfA[2][2], bfB[2][2];
    float4 a0, a1, a2, a3;   // half0 staging regs
    float4 b0, b1, b2, b3;   // half1 staging regs

    const int x0 = ((hi ^ (lr & 7)) << 4);
    const int x1 = (((4 + hi) ^ (lr & 7)) << 4);

    const int a_r0 = t >> 3;
    const int a_sl = t & 7;
    const int a_sw = ((a_sl ^ (a_r0 & 7)) << 4);

#define LA(H, KT, V0, V1, V2, V3) do { \
    const float* _p = Afp + (size_t)(bm0 + ((H) << 7) + a_r0) * K + ((KT) << 6) + (a_sl << 3); \
    V0 = *(const float4*)_p;                    V1 = *(const float4*)(_p + 4); \
    V2 = *(const float4*)(_p + (size_t)64 * K); V3 = *(const float4*)(_p + (size_t)64 * K + 4); \
} while (0)

#define WA(PAR, H, V0, V1, V2, V3) do { \
    char* _d = &lds[PAR][0][H][0]; \
    bf16x8 _h0, _h1; \
    _h0[0]=(bf16)V0.x; _h0[1]=(bf16)V0.y; _h0[2]=(bf16)V0.z; _h0[3]=(bf16)V0.w; \
    _h0[4]=(bf16)V1.x; _h0[5]=(bf16)V1.y; _h0[6]=(bf16)V1.z; _h0[7]=(bf16)V1.w; \
    _h1[0]=(bf16)V2.x; _h1[1]=(bf16)V2.y; _h1[2]=(bf16)V2.z; _h1[3]=(bf16)V2.w; \
    _h1[4]=(bf16)V3.x; _h1[5]=(bf16)V3.y; _h1[6]=(bf16)V3.z; _h1[7]=(bf16)V3.w; \
    *(bf16x8*)(_d + a_r0 * 128 + a_sw) = _h0; \
    *(bf16x8*)(_d + (64 + a_r0) * 128 + a_sw) = _h1; \
} while (0)

#define LDA_Q(MQ, PAR) do { \
    const char* _b = &lds[PAR][0][wm][0]; \
    _Pragma("unroll") \
    for (int m = 0; m < 4; ++m) { \
        const int _r = ((MQ) << 6) + (m << 4) + lr; \
        afq[m][0] = *(const bf16x8*)(_b + _r * 128 + x0); \
        afq[m][1] = *(const bf16x8*)(_b + _r * 128 + x1); \
    } \
} while (0)

#define LDB_Q(DST, NQ, PAR) do { \
    const char* _b = &lds[PAR][1][wn >> 1][0]; \
    _Pragma("unroll") \
    for (int n = 0; n < 2; ++n) { \
        const int _r = ((wn & 1) << 6) + ((((NQ) << 1) + n) << 4) + lr; \
        DST[n][0] = *(const bf16x8*)(_b + _r * 128 + x0); \
        DST[n][1] = *(const bf16x8*)(_b + _r * 128 + x1); \
    } \
} while (0)

#define MF_Q(MQ, NQ, BF) do { \
    __builtin_amdgcn_s_setprio(1); \
    _Pragma("unroll") \
    for (int ks = 0; ks < 2; ++ks) \
        _Pragma("unroll") \
        for (int m = 0; m < 4; ++m) { \
            acc[((MQ)<<2)+m][((NQ)<<1)+0] = __builtin_amdgcn_mfma_f32_16x16x32_bf16(afq[m][ks], BF[0][ks], acc[((MQ)<<2)+m][((NQ)<<1)+0], 0, 0, 0); \
            acc[((MQ)<<2)+m][((NQ)<<1)+1] = __builtin_amdgcn_mfma_f32_16x16x32_bf16(afq[m][ks], BF[1][ks], acc[((MQ)<<2)+m][((NQ)<<1)+1], 0, 0, 0); \
        } \
    __builtin_amdgcn_s_setprio(0); \
} while (0)

#define LGKM0()  asm volatile("s_waitcnt lgkmcnt(0)" ::: "memory")

    // ---------------- prologue ----------------
    // FIFO: LA0(4), LA1(4), SBpar0(4), SBpar1(4).  vmcnt(4): LA + par0-B done,
    // par1-B stays in flight (read at P4 of iter 0; drained by P2's auto-wait).
    LA(0, 0, a0, a1, a2, a3);
    LA(1, 0, b0, b1, b2, b3);
    stage_half(Bsrc[0], K, 0, &lds[0][1][0][0], t);
    stage_half(Bsrc[1], K, 0, &lds[0][1][1][0], t);
    stage_half(Bsrc[0], K, 1, &lds[1][1][0][0], t);
    stage_half(Bsrc[1], K, 1, &lds[1][1][1][0], t);
    WA(0, 0, a0, a1, a2, a3);
    WA(0, 1, b0, b1, b2, b3);
    asm volatile("s_waitcnt vmcnt(4)" ::: "memory");
    LGKM0();
    BAR();

    const int NI = K >> 7;   // 8 iterations, 2 K-tiles each
    for (int i = 0; i < NI; ++i) {
        const int  ktB  = 2 * i + 1;
        const bool last = (i == NI - 1);
        const int  kA2  = last ? 0 : 2 * i + 2;   // wrap: valid addr, dead data
        const int  kB2  = last ? 1 : 2 * i + 3;

        // P0
        LDA_Q(0, 0); LDB_Q(bfA, 0, 0);
        LA(0, ktB, a0, a1, a2, a3);               // 4 loads, consumed P2
        BAR(); MF_Q(0, 0, bfA); BAR();
        // P1
        LDB_Q(bfB, 1, 0);
        LA(1, ktB, b0, b1, b2, b3);               // 4 loads, consumed P3
        BAR(); MF_Q(0, 1, bfB); BAR();
        // P2
        LDA_Q(1, 0);
        WA(1, 0, a0, a1, a2, a3);                 // auto vmcnt(4): drains prev-P6 SB too
        stage_half(Bsrc[0], K, kA2, &lds[0][1][0][0], t);
        stage_half(Bsrc[1], K, kA2, &lds[0][1][1][0], t);
        BAR(); MF_Q(1, 1, bfB); BAR();
        // P3
        WA(1, 1, b0, b1, b2, b3);                 // auto vmcnt(4): P2-SB stays in flight
        LGKM0();
        BAR(); MF_Q(1, 0, bfA); BAR();
        // P4
        LDA_Q(0, 1); LDB_Q(bfA, 0, 1);
        LA(0, kA2, a0, a1, a2, a3);
        BAR(); MF_Q(0, 0, bfA); BAR();
        // P5
        LDB_Q(bfB, 1, 1);
        LA(1, kA2, b0, b1, b2, b3);
        BAR(); MF_Q(0, 1, bfB); BAR();
        // P6
        LDA_Q(1, 1);
        WA(0, 0, a0, a1, a2, a3);                 // auto vmcnt(4): drains P2-SB (read next P0)
        stage_half(Bsrc[0], K, kB2, &lds[1][1][0][0], t);
        stage_half(Bsrc[1], K, kB2, &lds[1][1][1][0], t);
        BAR(); MF_Q(1, 1, bfB); BAR();
        // P7
        WA(0, 1, b0, b1, b2, b3);                 // auto vmcnt(4): P6-SB stays in flight
        LGKM0();
        BAR(); MF_Q(1, 0, bfA); BAR();
    }

    // ---------------- epilogue ----------------
    const float alpha = *alphap;
    float bv[4];
    #pragma unroll
    for (int nf = 0; nf < 4; ++nf) bv[nf] = bias[bn0 + (wn << 6) + (nf << 4) + lr];

    #pragma unroll
    for (int mf = 0; mf < 8; ++mf) {
        const int grow = bm0 + (wm << 7) + (mf << 4) + (hi << 2);
        #pragma unroll
        for (int nf = 0; nf < 4; ++nf) {
            const int gcol = bn0 + (wn << 6) + (nf << 4) + lr;
            #pragma unroll
            for (int r = 0; r < 4; ++r)
                C[(size_t)(grow + r) * N + gcol] = alpha * acc[mf][nf][r] + bv[nf];
        }
    }
#undef LA
#undef WA
#undef LDA_Q
#undef LDB_Q
#undef MF_Q
#undef LGKM0
}

// ---------- fallback GEMM (round-1 proven): fp32 A staged in-kernel ----------
__global__ __launch_bounds__(256) void k_gemm_fb(const float* __restrict__ A,
                                                 const bf16* __restrict__ Bw,
                                                 const float* __restrict__ alphap,
                                                 const float* __restrict__ bias,
                                                 float* __restrict__ C,
                                                 int M, int N, int K) {
    __shared__ bf16 As[128 * 32];
    __shared__ bf16 Bs[128 * 32];
    const int t = threadIdx.x, lane = t & 63, wave = t >> 6;
    const int nbm = M >> 7;
    const int bm0 = (blockIdx.x % nbm) << 7;
    const int bn0 = (blockIdx.x / nbm) << 7;
    const int wr = (wave >> 1) << 6, wc = (wave & 1) << 6;
    f32x4 acc[4][4] = {};
    const int lr = lane & 15, lk = (lane >> 4) << 3;
    for (int k0 = 0; k0 < K; k0 += 32) {
        #pragma unroll
        for (int j = 0; j < 2; ++j) {
            const int c = t + j * 256;
            async_load16(Bw + (size_t)(bn0 + (c >> 2)) * K + k0 + ((c & 3) << 3),
                         (char*)Bs + j * 4096 + wave * 1024);
        }
        #pragma unroll
        for (int i = 0; i < 4; ++i) {
            const int idx = t + i * 256;
            const int row = idx >> 3, c4 = (idx & 7) << 2;
            const float4 v = *(const float4*)(A + (size_t)(bm0 + row) * K + k0 + c4);
            bf16x4 h;
            h[0] = (bf16)v.x; h[1] = (bf16)v.y; h[2] = (bf16)v.z; h[3] = (bf16)v.w;
            *(bf16x4*)(As + row * 32 + c4) = h;
        }
        __syncthreads();
        bf16x8 af[4], bfr[4];
        #pragma unroll
        for (int m = 0; m < 4; ++m) af[m] = *(const bf16x8*)(As + (wr + m * 16 + lr) * 32 + lk);
        #pragma unroll
        for (int n = 0; n < 4; ++n) bfr[n] = *(const bf16x8*)(Bs + (wc + n * 16 + lr) * 32 + lk);
        #pragma unroll
        for (int m = 0; m < 4; ++m)
            #pragma unroll
            for (int n = 0; n < 4; ++n)
                acc[m][n] = __builtin_amdgcn_mfma_f32_16x16x32_bf16(af[m], bfr[n], acc[m][n], 0, 0, 0);
        __syncthreads();
    }
    const float alpha = *alphap;
    #pragma unroll
    for (int m = 0; m < 4; ++m)
        #pragma unroll
        for (int n = 0; n < 4; ++n) {
            const int gcol = bn0 + wc + n * 16 + lr;
            const float bv = bias[gcol];
            #pragma unroll
            for (int r = 0; r < 4; ++r) {
                const int grow = bm0 + wr + m * 16 + ((lane >> 4) << 2) + r;
                C[(size_t)grow * N + gcol] = alpha * acc[m][n][r] + bv;
            }
        }
}

extern "C" void kernel_launch(void* const* d_in, const int* in_sizes, int n_in,
                              void* d_out, int out_size, void* d_ws, size_t ws_size,
                              hipStream_t stream) {
    const float* x     = (const float*)d_in[0];
    const float* wgt   = (const float*)d_in[1];
    const float* alpha = (const float*)d_in[2];
    const float* bias  = (const float*)d_in[3];
    float* out = (float*)d_out;

    const int wn   = in_sizes[1];        // 1048576
    const int dout = in_sizes[3];        // 1024
    const int din  = wn / dout;          // 1024
    const int m    = in_sizes[0] / din;  // 32768

    char* ws = (char*)d_ws;
    float*  delta = (float*)ws;                  // [0,4)
    double* part  = (double*)(ws + 64);          // 256 doubles
    bf16*   wt    = (bf16*)(ws + 8192);          // 2 MiB ternary weights

    k_abs_part<<<256, 256, 0, stream>>>(wgt, wn, part);
    k_delta<<<1, 256, 0, stream>>>(part, 256, wn, delta);
    k_quant<<<(wn / 4 + 255) / 256, 256, 0, stream>>>(wgt, delta, wt, wn / 4);

    if ((m % 256) == 0 && (dout % 256) == 0 && (din % 128) == 0) {
        dim3 grid((m / 256) * (dout / 256));
        k_gemm8<<<grid, 512, 0, stream>>>(x, wt, alpha, bias, out, m, dout, din);
    } else {
        dim3 grid((m / 128) * (dout / 128));
        k_gemm_fb<<<grid, 256, 0, stream>>>(x, wt, alpha, bias, out, m, dout, din);
    }
}

// Round 6
// 124.691 us; speedup vs baseline: 1.2909x; 1.1647x over previous
//
#include <hip/hip_runtime.h>
#include <hip/hip_bf16.h>

typedef __bf16 bf16;
typedef __attribute__((ext_vector_type(8))) __bf16 bf16x8;
typedef __attribute__((ext_vector_type(4))) __bf16 bf16x4;
typedef __attribute__((ext_vector_type(4))) float f32x4;

#define BAR() __builtin_amdgcn_s_barrier()

__device__ __forceinline__ void async_load16(const void* g, void* l) {
    __builtin_amdgcn_global_load_lds(
        (const __attribute__((address_space(1))) void*)g,
        (__attribute__((address_space(3))) void*)l, 16, 0, 0);
}

// ---------- kernel 1: per-block partial sum of |w| (deterministic tree) ----------
__global__ __launch_bounds__(256) void k_abs_part(const float* __restrict__ w, int n,
                                                  double* __restrict__ part) {
    __shared__ double sd[256];
    const int per_block = n / gridDim.x;
    const int base = blockIdx.x * per_block;
    double s = 0.0;
    for (int i = threadIdx.x; i < per_block; i += 256)
        s += (double)fabsf(w[base + i]);
    sd[threadIdx.x] = s;
    __syncthreads();
    for (int off = 128; off > 0; off >>= 1) {
        if (threadIdx.x < off) sd[threadIdx.x] += sd[threadIdx.x + off];
        __syncthreads();
    }
    if (threadIdx.x == 0) part[blockIdx.x] = sd[0];
}

// ---------- kernel 2: fused {delta finalize + W quantize + A fp32->bf16 convert} ----
// Every block re-reduces the 256 partials (2 KB, L2-hot, deterministic order) to get
// delta locally -> no separate k_delta launch.  Blocks [0,qb) quantize W; blocks
// [qb, grid) stream-convert A.  One launch instead of three.
__global__ __launch_bounds__(256) void k_quant_conv(const float* __restrict__ w,
                                                    const double* __restrict__ part,
                                                    bf16* __restrict__ wt, int n4,
                                                    const float* __restrict__ x,
                                                    bf16* __restrict__ abf, int na8,
                                                    int wn, int qb) {
    __shared__ double sd[256];
    sd[threadIdx.x] = part[threadIdx.x];
    __syncthreads();
    for (int off = 128; off > 0; off >>= 1) {
        if (threadIdx.x < off) sd[threadIdx.x] += sd[threadIdx.x + off];
        __syncthreads();
    }
    const float d = (float)(0.7 * sd[0] / (double)wn);

    if (blockIdx.x < qb) {
        // ---- quantize W: {-1,0,+1} in bf16 (exact) ----
        const int stride = qb * 256;
        for (int i = blockIdx.x * 256 + threadIdx.x; i < n4; i += stride) {
            const float4 v = ((const float4*)w)[i];
            bf16x4 o;
            o[0] = (bf16)((v.x > d) ? 1.0f : (v.x < -d) ? -1.0f : 0.0f);
            o[1] = (bf16)((v.y > d) ? 1.0f : (v.y < -d) ? -1.0f : 0.0f);
            o[2] = (bf16)((v.z > d) ? 1.0f : (v.z < -d) ? -1.0f : 0.0f);
            o[3] = (bf16)((v.w > d) ? 1.0f : (v.w < -d) ? -1.0f : 0.0f);
            *(bf16x4*)(wt + (size_t)i * 4) = o;
        }
    } else if (abf != nullptr) {
        // ---- convert A: 32 B/thread/iter streaming ----
        const int cb     = blockIdx.x - qb;
        const int stride = (gridDim.x - qb) * 256;
        for (int i = cb * 256 + threadIdx.x; i < na8; i += stride) {
            const float4 a = ((const float4*)x)[2 * i];
            const float4 b = ((const float4*)x)[2 * i + 1];
            bf16x8 h;
            h[0] = (bf16)a.x; h[1] = (bf16)a.y; h[2] = (bf16)a.z; h[3] = (bf16)a.w;
            h[4] = (bf16)b.x; h[5] = (bf16)b.y; h[6] = (bf16)b.z; h[7] = (bf16)b.w;
            ((bf16x8*)abf)[i] = h;
        }
    }
}

// ---------- helper: stage one 128x64 bf16 half-tile via global_load_lds ----------
// LDS dest linear (gload_lds requirement); swizzle achieved by inverse-permuting
// the GLOBAL source 16B-slot: s = (c&7) ^ (rowp&7). 512 thr x 2 loads = 1024 chunks.
__device__ __forceinline__ void stage_half(const bf16* __restrict__ srch, int K, int kt,
                                           char* dst, int t) {
    #pragma unroll
    for (int r = 0; r < 2; ++r) {
        const int c  = (r << 9) + t;
        const int rp = c >> 3;
        const int s  = (c & 7) ^ ((t >> 3) & 7);   // (rp&7) == ((t>>3)&7) since 64%8==0
        async_load16(srch + (size_t)rp * K + (kt << 6) + (s << 3), dst + (c << 4));
    }
}

// ---------- kernel 3: 256x256 8-phase bf16 GEMM (round-3 proven: 79us, MfmaUtil 33%) --
// C[m][n] = alpha * sum_k A[m][k]*Wt[n][k] + bias[n].  512 thr = 8 waves (2M x 4N),
// BK=64, LDS 128KB = 2 parity x {A,B} x 2 half(128x64).  Counted vmcnt(4) at P0/P4.
// Staging order: P0:HA0(ktB) P1:HA1(ktB) P2:HB0(ktA+2) P3:HB1(ktA+2)
// P4:HA0(ktA+2) P5:HA1(ktA+2) P6:HB0(ktB+2) P7:HB1(ktB+2).  Final iter wraps stage
// kt to 0/1 (valid addrs, dead data) so loop body + vmcnt counts stay uniform.
__global__ __launch_bounds__(512, 2) void k_gemm8(const bf16* __restrict__ A,
                                                  const bf16* __restrict__ Bw,
                                                  const float* __restrict__ alphap,
                                                  const float* __restrict__ bias,
                                                  float* __restrict__ C,
                                                  int M, int N, int K) {
    __shared__ __align__(16) char lds[2][2][2][16384];  // [parity][op A=0/B=1][half][16KB]

    const int t    = threadIdx.x;
    const int lane = t & 63;
    const int w    = t >> 6;
    const int wm   = w >> 2;          // 0/1: rows wm*128..+127
    const int wn   = w & 3;           // 0..3: cols wn*64..+63
    const int lr   = lane & 15;
    const int hi   = lane >> 4;

    // XCD-chunked, n-fastest: each XCD owns contiguous m-panels; A L2-reused 4x.
    const int nbn = N >> 8;                       // 4 n-tiles
    const int cpx = gridDim.x >> 3;
    const int lid = (blockIdx.x & 7) * cpx + (blockIdx.x >> 3);
    const int bn0 = (lid % nbn) << 8;
    const int bm0 = (lid / nbn) << 8;

    const bf16* Asrc[2] = { A  + (size_t)bm0 * K,  A  + (size_t)(bm0 + 128) * K };
    const bf16* Bsrc[2] = { Bw + (size_t)bn0 * K,  Bw + (size_t)(bn0 + 128) * K };

    f32x4 acc[8][4] = {};
    bf16x8 afq[4][2], bfA[2][2], bfB[2][2];

    // per-thread constant swizzled slot offsets: slot ks*4+hi, XOR row&7 == lr&7
    const int x0 = ((hi ^ (lr & 7)) << 4);
    const int x1 = (((4 + hi) ^ (lr & 7)) << 4);

#define LDA_Q(MQ, PAR) do { \
    const char* _b = &lds[PAR][0][wm][0]; \
    _Pragma("unroll") \
    for (int m = 0; m < 4; ++m) { \
        const int _r = ((MQ) << 6) + (m << 4) + lr; \
        afq[m][0] = *(const bf16x8*)(_b + _r * 128 + x0); \
        afq[m][1] = *(const bf16x8*)(_b + _r * 128 + x1); \
    } \
} while (0)

#define LDB_Q(DST, NQ, PAR) do { \
    const char* _b = &lds[PAR][1][wn >> 1][0]; \
    _Pragma("unroll") \
    for (int n = 0; n < 2; ++n) { \
        const int _r = ((wn & 1) << 6) + ((((NQ) << 1) + n) << 4) + lr; \
        DST[n][0] = *(const bf16x8*)(_b + _r * 128 + x0); \
        DST[n][1] = *(const bf16x8*)(_b + _r * 128 + x1); \
    } \
} while (0)

#define MF_Q(MQ, NQ, BF) do { \
    __builtin_amdgcn_s_setprio(1); \
    _Pragma("unroll") \
    for (int ks = 0; ks < 2; ++ks) \
        _Pragma("unroll") \
        for (int m = 0; m < 4; ++m) { \
            acc[((MQ)<<2)+m][((NQ)<<1)+0] = __builtin_amdgcn_mfma_f32_16x16x32_bf16(afq[m][ks], BF[0][ks], acc[((MQ)<<2)+m][((NQ)<<1)+0], 0, 0, 0); \
            acc[((MQ)<<2)+m][((NQ)<<1)+1] = __builtin_amdgcn_mfma_f32_16x16x32_bf16(afq[m][ks], BF[1][ks], acc[((MQ)<<2)+m][((NQ)<<1)+1], 0, 0, 0); \
        } \
    __builtin_amdgcn_s_setprio(0); \
} while (0)

#define VMCNT4() asm volatile("s_waitcnt vmcnt(4)" ::: "memory")

    // ---------------- prologue: kt0 all 4 halves, then kt1 B halves ----------------
    stage_half(Bsrc[0], K, 0, &lds[0][1][0][0], t);
    stage_half(Bsrc[1], K, 0, &lds[0][1][1][0], t);
    stage_half(Asrc[0], K, 0, &lds[0][0][0][0], t);
    stage_half(Asrc[1], K, 0, &lds[0][0][1][0], t);
    stage_half(Bsrc[0], K, 1, &lds[1][1][0][0], t);
    stage_half(Bsrc[1], K, 1, &lds[1][1][1][0], t);
    asm volatile("s_waitcnt vmcnt(0)" ::: "memory");
    BAR();

    const int NI = K >> 7;   // 8 iterations, 2 K-tiles each
    for (int i = 0; i < NI; ++i) {
        const int  ktB  = 2 * i + 1;
        const bool last = (i == NI - 1);
        const int  kA2  = last ? 0 : 2 * i + 2;   // wrap: valid addr, dead data
        const int  kB2  = last ? 1 : 2 * i + 3;

        // P0: quadrant (0,0) of ktA (parity 0)
        VMCNT4();
        LDA_Q(0, 0); LDB_Q(bfA, 0, 0);
        stage_half(Asrc[0], K, ktB, &lds[1][0][0][0], t);
        BAR(); MF_Q(0, 0, bfA); BAR();
        // P1: (0,1)
        LDB_Q(bfB, 1, 0);
        stage_half(Asrc[1], K, ktB, &lds[1][0][1][0], t);
        BAR(); MF_Q(0, 1, bfB); BAR();
        // P2: (1,1)
        LDA_Q(1, 0);
        stage_half(Bsrc[0], K, kA2, &lds[0][1][0][0], t);
        BAR(); MF_Q(1, 1, bfB); BAR();
        // P3: (1,0)
        stage_half(Bsrc[1], K, kA2, &lds[0][1][1][0], t);
        BAR(); MF_Q(1, 0, bfA); BAR();

        // P4: quadrant (0,0) of ktB (parity 1)
        VMCNT4();
        LDA_Q(0, 1); LDB_Q(bfA, 0, 1);
        stage_half(Asrc[0], K, kA2, &lds[0][0][0][0], t);
        BAR(); MF_Q(0, 0, bfA); BAR();
        // P5: (0,1)
        LDB_Q(bfB, 1, 1);
        stage_half(Asrc[1], K, kA2, &lds[0][0][1][0], t);
        BAR(); MF_Q(0, 1, bfB); BAR();
        // P6: (1,1)
        LDA_Q(1, 1);
        stage_half(Bsrc[0], K, kB2, &lds[1][1][0][0], t);
        BAR(); MF_Q(1, 1, bfB); BAR();
        // P7: (1,0)
        stage_half(Bsrc[1], K, kB2, &lds[1][1][1][0], t);
        BAR(); MF_Q(1, 0, bfA); BAR();
    }

    // ---------------- epilogue ----------------
    const float alpha = *alphap;
    float bv[4];
    #pragma unroll
    for (int nf = 0; nf < 4; ++nf) bv[nf] = bias[bn0 + (wn << 6) + (nf << 4) + lr];

    #pragma unroll
    for (int mf = 0; mf < 8; ++mf) {
        const int grow = bm0 + (wm << 7) + (mf << 4) + (hi << 2);
        #pragma unroll
        for (int nf = 0; nf < 4; ++nf) {
            const int gcol = bn0 + (wn << 6) + (nf << 4) + lr;
            #pragma unroll
            for (int r = 0; r < 4; ++r)
                C[(size_t)(grow + r) * N + gcol] = alpha * acc[mf][nf][r] + bv[nf];
        }
    }
#undef LDA_Q
#undef LDB_Q
#undef MF_Q
#undef VMCNT4
}

// ---------- fallback GEMM (round-1 proven): fp32 A staged in-kernel ----------
__global__ __launch_bounds__(256) void k_gemm_fb(const float* __restrict__ A,
                                                 const bf16* __restrict__ Bw,
                                                 const float* __restrict__ alphap,
                                                 const float* __restrict__ bias,
                                                 float* __restrict__ C,
                                                 int M, int N, int K) {
    __shared__ bf16 As[128 * 32];
    __shared__ bf16 Bs[128 * 32];
    const int t = threadIdx.x, lane = t & 63, wave = t >> 6;
    const int nbm = M >> 7;
    const int bm0 = (blockIdx.x % nbm) << 7;
    const int bn0 = (blockIdx.x / nbm) << 7;
    const int wr = (wave >> 1) << 6, wc = (wave & 1) << 6;
    f32x4 acc[4][4] = {};
    const int lr = lane & 15, lk = (lane >> 4) << 3;
    for (int k0 = 0; k0 < K; k0 += 32) {
        #pragma unroll
        for (int j = 0; j < 2; ++j) {
            const int c = t + j * 256;
            async_load16(Bw + (size_t)(bn0 + (c >> 2)) * K + k0 + ((c & 3) << 3),
                         (char*)Bs + j * 4096 + wave * 1024);
        }
        #pragma unroll
        for (int i = 0; i < 4; ++i) {
            const int idx = t + i * 256;
            const int row = idx >> 3, c4 = (idx & 7) << 2;
            const float4 v = *(const float4*)(A + (size_t)(bm0 + row) * K + k0 + c4);
            bf16x4 h;
            h[0] = (bf16)v.x; h[1] = (bf16)v.y; h[2] = (bf16)v.z; h[3] = (bf16)v.w;
            *(bf16x4*)(As + row * 32 + c4) = h;
        }
        __syncthreads();
        bf16x8 af[4], bfr[4];
        #pragma unroll
        for (int m = 0; m < 4; ++m) af[m] = *(const bf16x8*)(As + (wr + m * 16 + lr) * 32 + lk);
        #pragma unroll
        for (int n = 0; n < 4; ++n) bfr[n] = *(const bf16x8*)(Bs + (wc + n * 16 + lr) * 32 + lk);
        #pragma unroll
        for (int m = 0; m < 4; ++m)
            #pragma unroll
            for (int n = 0; n < 4; ++n)
                acc[m][n] = __builtin_amdgcn_mfma_f32_16x16x32_bf16(af[m], bfr[n], acc[m][n], 0, 0, 0);
        __syncthreads();
    }
    const float alpha = *alphap;
    #pragma unroll
    for (int m = 0; m < 4; ++m)
        #pragma unroll
        for (int n = 0; n < 4; ++n) {
            const int gcol = bn0 + wc + n * 16 + lr;
            const float bv = bias[gcol];
            #pragma unroll
            for (int r = 0; r < 4; ++r) {
                const int grow = bm0 + wr + m * 16 + ((lane >> 4) << 2) + r;
                C[(size_t)grow * N + gcol] = alpha * acc[m][n][r] + bv;
            }
        }
}

extern "C" void kernel_launch(void* const* d_in, const int* in_sizes, int n_in,
                              void* d_out, int out_size, void* d_ws, size_t ws_size,
                              hipStream_t stream) {
    const float* x     = (const float*)d_in[0];
    const float* wgt   = (const float*)d_in[1];
    const float* alpha = (const float*)d_in[2];
    const float* bias  = (const float*)d_in[3];
    float* out = (float*)d_out;

    const int wn   = in_sizes[1];        // 1048576
    const int dout = in_sizes[3];        // 1024
    const int din  = wn / dout;          // 1024
    const int m    = in_sizes[0] / din;  // 32768

    char* ws = (char*)d_ws;
    double* part = (double*)(ws + 64);          // 256 doubles
    bf16*   wt   = (bf16*)(ws + 8192);          // 2 MiB ternary weights
    bf16*   abf  = (bf16*)(ws + (4u << 20));    // 64 MiB bf16 A

    const size_t need = (4u << 20) + (size_t)in_sizes[0] * 2;
    const bool use8 = (ws_size >= need) && (m % 256) == 0 && (dout % 256) == 0 &&
                      (din % 128) == 0 && ((m / 256) * (dout / 256)) % 8 == 0;

    k_abs_part<<<256, 256, 0, stream>>>(wgt, wn, part);

    if (use8) {
        // blocks [0,1024): quantize W; [1024,3072): convert A fp32->bf16
        k_quant_conv<<<3072, 256, 0, stream>>>(wgt, part, wt, wn / 4,
                                               x, abf, in_sizes[0] / 8, wn, 1024);
        dim3 grid((m / 256) * (dout / 256));
        k_gemm8<<<grid, 512, 0, stream>>>(abf, wt, alpha, bias, out, m, dout, din);
    } else {
        k_quant_conv<<<1024, 256, 0, stream>>>(wgt, part, wt, wn / 4,
                                               nullptr, nullptr, 0, wn, 1024);
        dim3 grid((m / 128) * (dout / 128));
        k_gemm_fb<<<grid, 256, 0, stream>>>(x, wt, alpha, bias, out, m, dout, din);
    }
}

// Round 7
// 118.754 us; speedup vs baseline: 1.3554x; 1.0500x over previous
//
#include <hip/hip_runtime.h>
#include <hip/hip_bf16.h>

typedef __bf16 bf16;
typedef __attribute__((ext_vector_type(8))) __bf16 bf16x8;
typedef __attribute__((ext_vector_type(4))) __bf16 bf16x4;
typedef __attribute__((ext_vector_type(4))) float f32x4;

#define BAR() __builtin_amdgcn_s_barrier()

__device__ __forceinline__ void async_load16(const void* g, void* l) {
    __builtin_amdgcn_global_load_lds(
        (const __attribute__((address_space(1))) void*)g,
        (__attribute__((address_space(3))) void*)l, 16, 0, 0);
}

// ---------- kernel 1: fused {W |.| partials (blocks 0..255)} + {A fp32->bf16 (rest)} --
// The A-convert is independent of delta, so it runs in parallel with the W reduction.
// Blocks 0..255 produce the SAME deterministic partials as rounds 1-6.
__global__ __launch_bounds__(256) void k_absconv(const float* __restrict__ w, int wn,
                                                 double* __restrict__ part,
                                                 const float* __restrict__ x,
                                                 bf16* __restrict__ abf, int na8) {
    if (blockIdx.x < 256) {
        __shared__ double sd[256];
        const int per_block = wn / 256;
        const int base = blockIdx.x * per_block;
        double s = 0.0;
        for (int i = threadIdx.x; i < per_block; i += 256)
            s += (double)fabsf(w[base + i]);
        sd[threadIdx.x] = s;
        __syncthreads();
        for (int off = 128; off > 0; off >>= 1) {
            if (threadIdx.x < off) sd[threadIdx.x] += sd[threadIdx.x + off];
            __syncthreads();
        }
        if (threadIdx.x == 0) part[blockIdx.x] = sd[0];
    } else if (abf != nullptr) {
        const int cb     = blockIdx.x - 256;
        const int stride = (gridDim.x - 256) * 256;
        for (int i = cb * 256 + threadIdx.x; i < na8; i += stride) {
            const float4 a = ((const float4*)x)[2 * i];
            const float4 b = ((const float4*)x)[2 * i + 1];
            bf16x8 h;
            h[0] = (bf16)a.x; h[1] = (bf16)a.y; h[2] = (bf16)a.z; h[3] = (bf16)a.w;
            h[4] = (bf16)b.x; h[5] = (bf16)b.y; h[6] = (bf16)b.z; h[7] = (bf16)b.w;
            ((bf16x8*)abf)[i] = h;
        }
    }
}

// ---------- kernel 2: finalize delta locally + quantize W to ternary bf16 ----------
__global__ __launch_bounds__(256) void k_quantW(const float* __restrict__ w,
                                                const double* __restrict__ part,
                                                bf16* __restrict__ wt, int n4, int wn) {
    __shared__ double sd[256];
    sd[threadIdx.x] = part[threadIdx.x];
    __syncthreads();
    for (int off = 128; off > 0; off >>= 1) {
        if (threadIdx.x < off) sd[threadIdx.x] += sd[threadIdx.x + off];
        __syncthreads();
    }
    const float d = (float)(0.7 * sd[0] / (double)wn);
    const int stride = gridDim.x * 256;
    for (int i = blockIdx.x * 256 + threadIdx.x; i < n4; i += stride) {
        const float4 v = ((const float4*)w)[i];
        bf16x4 o;
        o[0] = (bf16)((v.x > d) ? 1.0f : (v.x < -d) ? -1.0f : 0.0f);
        o[1] = (bf16)((v.y > d) ? 1.0f : (v.y < -d) ? -1.0f : 0.0f);
        o[2] = (bf16)((v.z > d) ? 1.0f : (v.z < -d) ? -1.0f : 0.0f);
        o[3] = (bf16)((v.w > d) ? 1.0f : (v.w < -d) ? -1.0f : 0.0f);
        *(bf16x4*)(wt + (size_t)i * 4) = o;
    }
}

// ---------- helper: stage one 128x64 bf16 half-tile via global_load_lds ----------
// LDS dest linear (gload_lds requirement); swizzle achieved by inverse-permuting
// the GLOBAL source 16B-slot: s = (c&7) ^ (rowp&7). 512 thr x 2 loads = 1024 chunks.
__device__ __forceinline__ void stage_half(const bf16* __restrict__ srch, int K, int kt,
                                           char* dst, int t) {
    #pragma unroll
    for (int r = 0; r < 2; ++r) {
        const int c  = (r << 9) + t;
        const int rp = c >> 3;
        const int s  = (c & 7) ^ ((t >> 3) & 7);   // (rp&7) == ((t>>3)&7) since 64%8==0
        async_load16(srch + (size_t)rp * K + (kt << 6) + (s << 3), dst + (c << 4));
    }
}

// ---------- kernel 3: 256x256 8-phase bf16 GEMM (proven 79us core, + last-iter
// stage skip).  C[m][n] = alpha * sum_k A[m][k]*Wt[n][k] + bias[n].  512 thr =
// 8 waves (2M x 4N), BK=64, LDS 128KB, counted vmcnt(4) at P0/P4.
// Last iter: P0/P1 A-stages (ktB=K-1 tile, read at P4 this iter) kept; next-iter
// stages P2..P7 skipped; P4's wait becomes vmcnt(0) (the skipped P2/P3 stages
// were what made vmcnt(4) leave only dead loads outstanding).
__global__ __launch_bounds__(512, 2) void k_gemm8(const bf16* __restrict__ A,
                                                  const bf16* __restrict__ Bw,
                                                  const float* __restrict__ alphap,
                                                  const float* __restrict__ bias,
                                                  float* __restrict__ C,
                                                  int M, int N, int K) {
    __shared__ __align__(16) char lds[2][2][2][16384];  // [parity][op A=0/B=1][half][16KB]

    const int t    = threadIdx.x;
    const int lane = t & 63;
    const int w    = t >> 6;
    const int wm   = w >> 2;          // 0/1: rows wm*128..+127
    const int wn   = w & 3;           // 0..3: cols wn*64..+63
    const int lr   = lane & 15;
    const int hi   = lane >> 4;

    // XCD-chunked, n-fastest: each XCD owns contiguous m-panels; A L2-reused 4x.
    const int nbn = N >> 8;                       // 4 n-tiles
    const int cpx = gridDim.x >> 3;
    const int lid = (blockIdx.x & 7) * cpx + (blockIdx.x >> 3);
    const int bn0 = (lid % nbn) << 8;
    const int bm0 = (lid / nbn) << 8;

    const bf16* Asrc[2] = { A  + (size_t)bm0 * K,  A  + (size_t)(bm0 + 128) * K };
    const bf16* Bsrc[2] = { Bw + (size_t)bn0 * K,  Bw + (size_t)(bn0 + 128) * K };

    f32x4 acc[8][4] = {};
    bf16x8 afq[4][2], bfA[2][2], bfB[2][2];

    // per-thread constant swizzled slot offsets: slot ks*4+hi, XOR row&7 == lr&7
    const int x0 = ((hi ^ (lr & 7)) << 4);
    const int x1 = (((4 + hi) ^ (lr & 7)) << 4);

#define LDA_Q(MQ, PAR) do { \
    const char* _b = &lds[PAR][0][wm][0]; \
    _Pragma("unroll") \
    for (int m = 0; m < 4; ++m) { \
        const int _r = ((MQ) << 6) + (m << 4) + lr; \
        afq[m][0] = *(const bf16x8*)(_b + _r * 128 + x0); \
        afq[m][1] = *(const bf16x8*)(_b + _r * 128 + x1); \
    } \
} while (0)

#define LDB_Q(DST, NQ, PAR) do { \
    const char* _b = &lds[PAR][1][wn >> 1][0]; \
    _Pragma("unroll") \
    for (int n = 0; n < 2; ++n) { \
        const int _r = ((wn & 1) << 6) + ((((NQ) << 1) + n) << 4) + lr; \
        DST[n][0] = *(const bf16x8*)(_b + _r * 128 + x0); \
        DST[n][1] = *(const bf16x8*)(_b + _r * 128 + x1); \
    } \
} while (0)

#define MF_Q(MQ, NQ, BF) do { \
    __builtin_amdgcn_s_setprio(1); \
    _Pragma("unroll") \
    for (int ks = 0; ks < 2; ++ks) \
        _Pragma("unroll") \
        for (int m = 0; m < 4; ++m) { \
            acc[((MQ)<<2)+m][((NQ)<<1)+0] = __builtin_amdgcn_mfma_f32_16x16x32_bf16(afq[m][ks], BF[0][ks], acc[((MQ)<<2)+m][((NQ)<<1)+0], 0, 0, 0); \
            acc[((MQ)<<2)+m][((NQ)<<1)+1] = __builtin_amdgcn_mfma_f32_16x16x32_bf16(afq[m][ks], BF[1][ks], acc[((MQ)<<2)+m][((NQ)<<1)+1], 0, 0, 0); \
        } \
    __builtin_amdgcn_s_setprio(0); \
} while (0)

#define VMCNT4() asm volatile("s_waitcnt vmcnt(4)" ::: "memory")
#define VMCNT0() asm volatile("s_waitcnt vmcnt(0)" ::: "memory")

    // ---------------- prologue: kt0 all 4 halves, then kt1 B halves ----------------
    stage_half(Bsrc[0], K, 0, &lds[0][1][0][0], t);
    stage_half(Bsrc[1], K, 0, &lds[0][1][1][0], t);
    stage_half(Asrc[0], K, 0, &lds[0][0][0][0], t);
    stage_half(Asrc[1], K, 0, &lds[0][0][1][0], t);
    stage_half(Bsrc[0], K, 1, &lds[1][1][0][0], t);
    stage_half(Bsrc[1], K, 1, &lds[1][1][1][0], t);
    VMCNT0();
    BAR();

    const int NI = K >> 7;   // 8 iterations, 2 K-tiles each
    for (int i = 0; i < NI; ++i) {
        const int  ktB  = 2 * i + 1;
        const bool last = (i == NI - 1);
        const int  kA2  = 2 * i + 2;
        const int  kB2  = 2 * i + 3;

        // P0: quadrant (0,0) of ktA (parity 0)
        VMCNT4();
        LDA_Q(0, 0); LDB_Q(bfA, 0, 0);
        stage_half(Asrc[0], K, ktB, &lds[1][0][0][0], t);
        BAR(); MF_Q(0, 0, bfA); BAR();
        // P1: (0,1)
        LDB_Q(bfB, 1, 0);
        stage_half(Asrc[1], K, ktB, &lds[1][0][1][0], t);
        BAR(); MF_Q(0, 1, bfB); BAR();
        // P2: (1,1)
        LDA_Q(1, 0);
        if (!last) stage_half(Bsrc[0], K, kA2, &lds[0][1][0][0], t);
        BAR(); MF_Q(1, 1, bfB); BAR();
        // P3: (1,0)
        if (!last) stage_half(Bsrc[1], K, kA2, &lds[0][1][1][0], t);
        BAR(); MF_Q(1, 0, bfA); BAR();

        // P4: quadrant (0,0) of ktB (parity 1)
        if (last) { VMCNT0(); } else { VMCNT4(); }
        LDA_Q(0, 1); LDB_Q(bfA, 0, 1);
        if (!last) stage_half(Asrc[0], K, kA2, &lds[0][0][0][0], t);
        BAR(); MF_Q(0, 0, bfA); BAR();
        // P5: (0,1)
        LDB_Q(bfB, 1, 1);
        if (!last) stage_half(Asrc[1], K, kA2, &lds[0][0][1][0], t);
        BAR(); MF_Q(0, 1, bfB); BAR();
        // P6: (1,1)
        LDA_Q(1, 1);
        if (!last) stage_half(Bsrc[0], K, kB2, &lds[1][1][0][0], t);
        BAR(); MF_Q(1, 1, bfB); BAR();
        // P7: (1,0)
        if (!last) stage_half(Bsrc[1], K, kB2, &lds[1][1][1][0], t);
        BAR(); MF_Q(1, 0, bfA); BAR();
    }

    // ---------------- epilogue ----------------
    const float alpha = *alphap;
    float bv[4];
    #pragma unroll
    for (int nf = 0; nf < 4; ++nf) bv[nf] = bias[bn0 + (wn << 6) + (nf << 4) + lr];

    #pragma unroll
    for (int mf = 0; mf < 8; ++mf) {
        const int grow = bm0 + (wm << 7) + (mf << 4) + (hi << 2);
        #pragma unroll
        for (int nf = 0; nf < 4; ++nf) {
            const int gcol = bn0 + (wn << 6) + (nf << 4) + lr;
            #pragma unroll
            for (int r = 0; r < 4; ++r)
                C[(size_t)(grow + r) * N + gcol] = alpha * acc[mf][nf][r] + bv[nf];
        }
    }
#undef LDA_Q
#undef LDB_Q
#undef MF_Q
#undef VMCNT4
#undef VMCNT0
}

// ---------- fallback GEMM (round-1 proven): fp32 A staged in-kernel ----------
__global__ __launch_bounds__(256) void k_gemm_fb(const float* __restrict__ A,
                                                 const bf16* __restrict__ Bw,
                                                 const float* __restrict__ alphap,
                                                 const float* __restrict__ bias,
                                                 float* __restrict__ C,
                                                 int M, int N, int K) {
    __shared__ bf16 As[128 * 32];
    __shared__ bf16 Bs[128 * 32];
    const int t = threadIdx.x, lane = t & 63, wave = t >> 6;
    const int nbm = M >> 7;
    const int bm0 = (blockIdx.x % nbm) << 7;
    const int bn0 = (blockIdx.x / nbm) << 7;
    const int wr = (wave >> 1) << 6, wc = (wave & 1) << 6;
    f32x4 acc[4][4] = {};
    const int lr = lane & 15, lk = (lane >> 4) << 3;
    for (int k0 = 0; k0 < K; k0 += 32) {
        #pragma unroll
        for (int j = 0; j < 2; ++j) {
            const int c = t + j * 256;
            async_load16(Bw + (size_t)(bn0 + (c >> 2)) * K + k0 + ((c & 3) << 3),
                         (char*)Bs + j * 4096 + wave * 1024);
        }
        #pragma unroll
        for (int i = 0; i < 4; ++i) {
            const int idx = t + i * 256;
            const int row = idx >> 3, c4 = (idx & 7) << 2;
            const float4 v = *(const float4*)(A + (size_t)(bm0 + row) * K + k0 + c4);
            bf16x4 h;
            h[0] = (bf16)v.x; h[1] = (bf16)v.y; h[2] = (bf16)v.z; h[3] = (bf16)v.w;
            *(bf16x4*)(As + row * 32 + c4) = h;
        }
        __syncthreads();
        bf16x8 af[4], bfr[4];
        #pragma unroll
        for (int m = 0; m < 4; ++m) af[m] = *(const bf16x8*)(As + (wr + m * 16 + lr) * 32 + lk);
        #pragma unroll
        for (int n = 0; n < 4; ++n) bfr[n] = *(const bf16x8*)(Bs + (wc + n * 16 + lr) * 32 + lk);
        #pragma unroll
        for (int m = 0; m < 4; ++m)
            #pragma unroll
            for (int n = 0; n < 4; ++n)
                acc[m][n] = __builtin_amdgcn_mfma_f32_16x16x32_bf16(af[m], bfr[n], acc[m][n], 0, 0, 0);
        __syncthreads();
    }
    const float alpha = *alphap;
    #pragma unroll
    for (int m = 0; m < 4; ++m)
        #pragma unroll
        for (int n = 0; n < 4; ++n) {
            const int gcol = bn0 + wc + n * 16 + lr;
            const float bv = bias[gcol];
            #pragma unroll
            for (int r = 0; r < 4; ++r) {
                const int grow = bm0 + wr + m * 16 + ((lane >> 4) << 2) + r;
                C[(size_t)grow * N + gcol] = alpha * acc[m][n][r] + bv;
            }
        }
}

extern "C" void kernel_launch(void* const* d_in, const int* in_sizes, int n_in,
                              void* d_out, int out_size, void* d_ws, size_t ws_size,
                              hipStream_t stream) {
    const float* x     = (const float*)d_in[0];
    const float* wgt   = (const float*)d_in[1];
    const float* alpha = (const float*)d_in[2];
    const float* bias  = (const float*)d_in[3];
    float* out = (float*)d_out;

    const int wn   = in_sizes[1];        // 1048576
    const int dout = in_sizes[3];        // 1024
    const int din  = wn / dout;          // 1024
    const int m    = in_sizes[0] / din;  // 32768

    char* ws = (char*)d_ws;
    double* part = (double*)(ws + 64);          // 256 doubles
    bf16*   wt   = (bf16*)(ws + 8192);          // 2 MiB ternary weights
    bf16*   abf  = (bf16*)(ws + (4u << 20));    // 64 MiB bf16 A

    const size_t need = (4u << 20) + (size_t)in_sizes[0] * 2;
    const bool use8 = (ws_size >= need) && (m % 256) == 0 && (dout % 256) == 0 &&
                      (din % 128) == 0 && ((m / 256) * (dout / 256)) % 8 == 0;

    if (use8) {
        k_absconv<<<2304, 256, 0, stream>>>(wgt, wn, part, x, abf, in_sizes[0] / 8);
        k_quantW<<<512, 256, 0, stream>>>(wgt, part, wt, wn / 4, wn);
        dim3 grid((m / 256) * (dout / 256));
        k_gemm8<<<grid, 512, 0, stream>>>(abf, wt, alpha, bias, out, m, dout, din);
    } else {
        k_absconv<<<256, 256, 0, stream>>>(wgt, wn, part, x, nullptr, 0);
        k_quantW<<<512, 256, 0, stream>>>(wgt, part, wt, wn / 4, wn);
        dim3 grid((m / 128) * (dout / 128));
        k_gemm_fb<<<grid, 256, 0, stream>>>(x, wt, alpha, bias, out, m, dout, din);
    }
}

// Round 8
// 115.749 us; speedup vs baseline: 1.3906x; 1.0260x over previous
//
#include <hip/hip_runtime.h>
#include <hip/hip_bf16.h>

typedef __bf16 bf16;
typedef __attribute__((ext_vector_type(8))) __bf16 bf16x8;
typedef __attribute__((ext_vector_type(4))) __bf16 bf16x4;
typedef __attribute__((ext_vector_type(4))) float f32x4;

#define BAR() __builtin_amdgcn_s_barrier()

__device__ __forceinline__ void async_load16(const void* g, void* l) {
    __builtin_amdgcn_global_load_lds(
        (const __attribute__((address_space(1))) void*)g,
        (__attribute__((address_space(3))) void*)l, 16, 0, 0);
}

// ---------- kernel 1: fused {W |.| partials (blocks 0..255)} + {A fp32->bf16 (rest)} --
__global__ __launch_bounds__(256) void k_absconv(const float* __restrict__ w, int wn,
                                                 double* __restrict__ part,
                                                 const float* __restrict__ x,
                                                 bf16* __restrict__ abf, int na8) {
    if (blockIdx.x < 256) {
        __shared__ double sd[256];
        const int per_block = wn / 256;
        const int base = blockIdx.x * per_block;
        double s = 0.0;
        for (int i = threadIdx.x; i < per_block; i += 256)
            s += (double)fabsf(w[base + i]);
        sd[threadIdx.x] = s;
        __syncthreads();
        for (int off = 128; off > 0; off >>= 1) {
            if (threadIdx.x < off) sd[threadIdx.x] += sd[threadIdx.x + off];
            __syncthreads();
        }
        if (threadIdx.x == 0) part[blockIdx.x] = sd[0];
    } else if (abf != nullptr) {
        const int cb     = blockIdx.x - 256;
        const int stride = (gridDim.x - 256) * 256;
        for (int i = cb * 256 + threadIdx.x; i < na8; i += stride) {
            const float4 a = ((const float4*)x)[2 * i];
            const float4 b = ((const float4*)x)[2 * i + 1];
            bf16x8 h;
            h[0] = (bf16)a.x; h[1] = (bf16)a.y; h[2] = (bf16)a.z; h[3] = (bf16)a.w;
            h[4] = (bf16)b.x; h[5] = (bf16)b.y; h[6] = (bf16)b.z; h[7] = (bf16)b.w;
            ((bf16x8*)abf)[i] = h;
        }
    }
}

// ---------- kernel 2: finalize delta locally + quantize W to ternary bf16 ----------
__global__ __launch_bounds__(256) void k_quantW(const float* __restrict__ w,
                                                const double* __restrict__ part,
                                                bf16* __restrict__ wt, int n4, int wn) {
    __shared__ double sd[256];
    sd[threadIdx.x] = part[threadIdx.x];
    __syncthreads();
    for (int off = 128; off > 0; off >>= 1) {
        if (threadIdx.x < off) sd[threadIdx.x] += sd[threadIdx.x + off];
        __syncthreads();
    }
    const float d = (float)(0.7 * sd[0] / (double)wn);
    const int stride = gridDim.x * 256;
    for (int i = blockIdx.x * 256 + threadIdx.x; i < n4; i += stride) {
        const float4 v = ((const float4*)w)[i];
        bf16x4 o;
        o[0] = (bf16)((v.x > d) ? 1.0f : (v.x < -d) ? -1.0f : 0.0f);
        o[1] = (bf16)((v.y > d) ? 1.0f : (v.y < -d) ? -1.0f : 0.0f);
        o[2] = (bf16)((v.z > d) ? 1.0f : (v.z < -d) ? -1.0f : 0.0f);
        o[3] = (bf16)((v.w > d) ? 1.0f : (v.w < -d) ? -1.0f : 0.0f);
        *(bf16x4*)(wt + (size_t)i * 4) = o;
    }
}

// ---------- helper: stage one 128x64 bf16 half-tile via global_load_lds ----------
// Linear LDS dest (gload_lds requirement); swizzle via inverse-permuted GLOBAL
// source 16B-slot: s = (c&7) ^ (row&7).  512 thr x 2 loads = 1024 chunks.
__device__ __forceinline__ void stage_half(const bf16* __restrict__ srch, int K, int kt,
                                           char* dst, int t) {
    #pragma unroll
    for (int r = 0; r < 2; ++r) {
        const int c  = (r << 9) + t;
        const int rp = c >> 3;
        const int s  = (c & 7) ^ ((t >> 3) & 7);   // (rp&7) == ((t>>3)&7) since 64%8==0
        async_load16(srch + (size_t)rp * K + (kt << 6) + (s << 3), dst + (c << 4));
    }
}

// ---------- kernel 3: 128x256 tile, 2-phase, single-buffer, 2 blocks/CU ----------
// C[m][n] = alpha * sum_k A[m][k]*Wt[n][k] + bias[n].
// 512 thr = 8 waves (2M x 4N), wave tile 64x64 (acc = 64 f32 -> fits 128-reg
// budget at 4 waves/SIMD).  LDS 48KB single-buffered, BK=64, XOR-swizzled.
// Per K-tile: rd ks0 -> MFMA ks0 -> rd ks1 (reg reuse) -> lgkm0+BAR (reads
// drained before DMA overwrite) -> stage t+1 -> MFMA ks1 (regs, hides stage)
// -> vmcnt0+BAR.  The vmcnt(0) drain overlaps the co-resident block's MFMA
// (m97 mechanism); block-exit stagger overlaps epilogue C-writes with compute.
__global__ __launch_bounds__(512, 4) void k_gemm2(const bf16* __restrict__ A,
                                                  const bf16* __restrict__ Bw,
                                                  const float* __restrict__ alphap,
                                                  const float* __restrict__ bias,
                                                  float* __restrict__ C,
                                                  int M, int N, int K) {
    __shared__ __align__(16) char As[16384];    // 128 x 64 bf16, swizzled
    __shared__ __align__(16) char Bs[32768];    // 256 x 64 bf16, swizzled

    const int t    = threadIdx.x;
    const int lane = t & 63;
    const int w    = t >> 6;
    const int wm   = w >> 2;          // 0/1: rows wm*64..+63
    const int wn   = w & 3;           // 0..3: cols wn*64..+63
    const int lr   = lane & 15;
    const int hi   = lane >> 4;

    // XCD-chunked, n-fastest: XCD owns contiguous m-panels; A L2/L3-reused 4x.
    const int nbn = N >> 8;                       // 4 n-tiles
    const int cpx = gridDim.x >> 3;
    const int lid = (blockIdx.x & 7) * cpx + (blockIdx.x >> 3);
    const int bn0 = (lid % nbn) << 8;
    const int bm0 = (lid / nbn) << 7;             // BM = 128

    const bf16* Asrc  = A  + (size_t)bm0 * K;
    const bf16* Bsrc0 = Bw + (size_t)bn0 * K;
    const bf16* Bsrc1 = Bw + (size_t)(bn0 + 128) * K;

    f32x4 acc[4][4] = {};
    bf16x8 af[4], bf[4];

    const int x0 = ((hi ^ (lr & 7)) << 4);        // ks0 swizzled slot offset
    const int x1 = (((4 + hi) ^ (lr & 7)) << 4);  // ks1

#define RDA(XS) do { \
    _Pragma("unroll") \
    for (int m = 0; m < 4; ++m) { \
        const int _r = (wm << 6) + (m << 4) + lr; \
        af[m] = *(const bf16x8*)(As + _r * 128 + (XS)); \
    } \
} while (0)

#define RDB(XS) do { \
    _Pragma("unroll") \
    for (int n = 0; n < 4; ++n) { \
        const int _r = (wn << 6) + (n << 4) + lr; \
        bf[n] = *(const bf16x8*)(Bs + _r * 128 + (XS)); \
    } \
} while (0)

#define MF16() do { \
    __builtin_amdgcn_s_setprio(1); \
    _Pragma("unroll") \
    for (int m = 0; m < 4; ++m) \
        _Pragma("unroll") \
        for (int n = 0; n < 4; ++n) \
            acc[m][n] = __builtin_amdgcn_mfma_f32_16x16x32_bf16(af[m], bf[n], acc[m][n], 0, 0, 0); \
    __builtin_amdgcn_s_setprio(0); \
} while (0)

#define VMCNT0() asm volatile("s_waitcnt vmcnt(0)" ::: "memory")
#define LGKM0()  asm volatile("s_waitcnt lgkmcnt(0)" ::: "memory")

    // ---------------- prologue: stage tile 0 ----------------
    stage_half(Asrc,  K, 0, As, t);
    stage_half(Bsrc0, K, 0, Bs, t);
    stage_half(Bsrc1, K, 0, Bs + 16384, t);
    VMCNT0();
    BAR();

    const int NT = K >> 6;   // 16 K-tiles
    for (int kt = 0; kt < NT; ++kt) {
        const bool more = (kt + 1) < NT;

        RDA(x0); RDB(x0);
        MF16();                       // ks0 (LDS latency hidden by 4 waves/SIMD)
        RDA(x1); RDB(x1);             // ks1 into same regs (ks0 frags dead)
        LGKM0();                      // all this wave's LDS reads complete
        BAR();                        // all waves done reading the buffer
        if (more) {
            stage_half(Asrc,  K, kt + 1, As, t);
            stage_half(Bsrc0, K, kt + 1, Bs, t);
            stage_half(Bsrc1, K, kt + 1, Bs + 16384, t);
        }
        MF16();                       // ks1 on regs; stage DMA flies underneath
        if (more) { VMCNT0(); }       // stage complete (drain overlaps co-block)
        BAR();
    }

    // ---------------- epilogue: alpha * acc + bias ----------------
    const float alpha = *alphap;
    float bv[4];
    #pragma unroll
    for (int nf = 0; nf < 4; ++nf) bv[nf] = bias[bn0 + (wn << 6) + (nf << 4) + lr];

    #pragma unroll
    for (int mf = 0; mf < 4; ++mf) {
        const int grow = bm0 + (wm << 6) + (mf << 4) + (hi << 2);
        #pragma unroll
        for (int nf = 0; nf < 4; ++nf) {
            const int gcol = bn0 + (wn << 6) + (nf << 4) + lr;
            #pragma unroll
            for (int r = 0; r < 4; ++r)
                C[(size_t)(grow + r) * N + gcol] = alpha * acc[mf][nf][r] + bv[nf];
        }
    }
#undef RDA
#undef RDB
#undef MF16
#undef VMCNT0
#undef LGKM0
}

// ---------- fallback GEMM (round-1 proven): fp32 A staged in-kernel ----------
__global__ __launch_bounds__(256) void k_gemm_fb(const float* __restrict__ A,
                                                 const bf16* __restrict__ Bw,
                                                 const float* __restrict__ alphap,
                                                 const float* __restrict__ bias,
                                                 float* __restrict__ C,
                                                 int M, int N, int K) {
    __shared__ bf16 As[128 * 32];
    __shared__ bf16 Bs[128 * 32];
    const int t = threadIdx.x, lane = t & 63, wave = t >> 6;
    const int nbm = M >> 7;
    const int bm0 = (blockIdx.x % nbm) << 7;
    const int bn0 = (blockIdx.x / nbm) << 7;
    const int wr = (wave >> 1) << 6, wc = (wave & 1) << 6;
    f32x4 acc[4][4] = {};
    const int lr = lane & 15, lk = (lane >> 4) << 3;
    for (int k0 = 0; k0 < K; k0 += 32) {
        #pragma unroll
        for (int j = 0; j < 2; ++j) {
            const int c = t + j * 256;
            async_load16(Bw + (size_t)(bn0 + (c >> 2)) * K + k0 + ((c & 3) << 3),
                         (char*)Bs + j * 4096 + wave * 1024);
        }
        #pragma unroll
        for (int i = 0; i < 4; ++i) {
            const int idx = t + i * 256;
            const int row = idx >> 3, c4 = (idx & 7) << 2;
            const float4 v = *(const float4*)(A + (size_t)(bm0 + row) * K + k0 + c4);
            bf16x4 h;
            h[0] = (bf16)v.x; h[1] = (bf16)v.y; h[2] = (bf16)v.z; h[3] = (bf16)v.w;
            *(bf16x4*)(As + row * 32 + c4) = h;
        }
        __syncthreads();
        bf16x8 af[4], bfr[4];
        #pragma unroll
        for (int m = 0; m < 4; ++m) af[m] = *(const bf16x8*)(As + (wr + m * 16 + lr) * 32 + lk);
        #pragma unroll
        for (int n = 0; n < 4; ++n) bfr[n] = *(const bf16x8*)(Bs + (wc + n * 16 + lr) * 32 + lk);
        #pragma unroll
        for (int m = 0; m < 4; ++m)
            #pragma unroll
            for (int n = 0; n < 4; ++n)
                acc[m][n] = __builtin_amdgcn_mfma_f32_16x16x32_bf16(af[m], bfr[n], acc[m][n], 0, 0, 0);
        __syncthreads();
    }
    const float alpha = *alphap;
    #pragma unroll
    for (int m = 0; m < 4; ++m)
        #pragma unroll
        for (int n = 0; n < 4; ++n) {
            const int gcol = bn0 + wc + n * 16 + lr;
            const float bv = bias[gcol];
            #pragma unroll
            for (int r = 0; r < 4; ++r) {
                const int grow = bm0 + wr + m * 16 + ((lane >> 4) << 2) + r;
                C[(size_t)grow * N + gcol] = alpha * acc[m][n][r] + bv;
            }
        }
}

extern "C" void kernel_launch(void* const* d_in, const int* in_sizes, int n_in,
                              void* d_out, int out_size, void* d_ws, size_t ws_size,
                              hipStream_t stream) {
    const float* x     = (const float*)d_in[0];
    const float* wgt   = (const float*)d_in[1];
    const float* alpha = (const float*)d_in[2];
    const float* bias  = (const float*)d_in[3];
    float* out = (float*)d_out;

    const int wn   = in_sizes[1];        // 1048576
    const int dout = in_sizes[3];        // 1024
    const int din  = wn / dout;          // 1024
    const int m    = in_sizes[0] / din;  // 32768

    char* ws = (char*)d_ws;
    double* part = (double*)(ws + 64);          // 256 doubles
    bf16*   wt   = (bf16*)(ws + 8192);          // 2 MiB ternary weights
    bf16*   abf  = (bf16*)(ws + (4u << 20));    // 64 MiB bf16 A

    const size_t need = (4u << 20) + (size_t)in_sizes[0] * 2;
    const bool use2 = (ws_size >= need) && (m % 128) == 0 && (dout % 256) == 0 &&
                      (din % 64) == 0 && ((m / 128) * (dout / 256)) % 8 == 0;

    if (use2) {
        k_absconv<<<2304, 256, 0, stream>>>(wgt, wn, part, x, abf, in_sizes[0] / 8);
        k_quantW<<<512, 256, 0, stream>>>(wgt, part, wt, wn / 4, wn);
        dim3 grid((m / 128) * (dout / 256));
        k_gemm2<<<grid, 512, 0, stream>>>(abf, wt, alpha, bias, out, m, dout, din);
    } else {
        k_absconv<<<256, 256, 0, stream>>>(wgt, wn, part, x, nullptr, 0);
        k_quantW<<<512, 256, 0, stream>>>(wgt, part, wt, wn / 4, wn);
        dim3 grid((m / 128) * (dout / 128));
        k_gemm_fb<<<grid, 256, 0, stream>>>(x, wt, alpha, bias, out, m, dout, din);
    }
}